// Round 1
// baseline (2225.932 us; speedup 1.0000x reference)
//
#include <hip/hip_runtime.h>
#include <hip/hip_bf16.h>
#include <math.h>

#define BATCH 2
#define SEQ 2048
#define EMBED 1024
#define NHEAD 16
#define HDIM 64
#define M_TOK (BATCH*SEQ)          // 4096 tokens
#define QKV_N (3*EMBED)            // 3072
#define OUT_ELEMS ((size_t)M_TOK*EMBED)   // 4,194,304

// ---------------------------------------------------------------------------
// Generic tiled fp32 GEMM with bias: C[M,N] = A[M,K] @ B[K,N] + bias[N]
// 64x64 tile, BK=16, 256 threads, 4x4 per thread. M,N,K multiples of 64/16.
// ---------------------------------------------------------------------------
__global__ __launch_bounds__(256) void gemm_bias_kernel(
    const float* __restrict__ A, const float* __restrict__ B,
    const float* __restrict__ bias, float* __restrict__ C,
    int M, int N, int K)
{
    __shared__ float As[16][64];      // As[k][m]
    __shared__ float Bs[16][64 + 1];  // Bs[k][n] (+1 pad)
    const int tx = threadIdx.x & 15;
    const int ty = threadIdx.x >> 4;
    const int row0 = blockIdx.y * 64;
    const int col0 = blockIdx.x * 64;

    float acc[4][4] = {};
    for (int k0 = 0; k0 < K; k0 += 16) {
        for (int i = threadIdx.x; i < 64 * 16; i += 256) {
            int m = i >> 4, kk = i & 15;
            As[kk][m] = A[(size_t)(row0 + m) * K + (k0 + kk)];
        }
        for (int i = threadIdx.x; i < 64 * 16; i += 256) {
            int kk = i >> 6, n = i & 63;
            Bs[kk][n] = B[(size_t)(k0 + kk) * N + (col0 + n)];
        }
        __syncthreads();
        #pragma unroll
        for (int kk = 0; kk < 16; ++kk) {
            float a[4], b[4];
            #pragma unroll
            for (int i = 0; i < 4; ++i) a[i] = As[kk][ty * 4 + i];
            #pragma unroll
            for (int j = 0; j < 4; ++j) b[j] = Bs[kk][tx * 4 + j];
            #pragma unroll
            for (int i = 0; i < 4; ++i)
                #pragma unroll
                for (int j = 0; j < 4; ++j)
                    acc[i][j] += a[i] * b[j];
        }
        __syncthreads();
    }
    #pragma unroll
    for (int i = 0; i < 4; ++i) {
        int m = row0 + ty * 4 + i;
        #pragma unroll
        for (int j = 0; j < 4; ++j) {
            int n = col0 + tx * 4 + j;
            C[(size_t)m * N + n] = acc[i][j] + bias[n];
        }
    }
}

// ---------------------------------------------------------------------------
// Scores: S[bh,q,k] = (Q . K) / 8, masked (k>q -> -inf). Only tiles kt<=qt.
// qkv layout: [tok, 3072]; Q at col h*64+d, K at 1024+h*64+d.
// ---------------------------------------------------------------------------
__global__ __launch_bounds__(256) void scores_kernel(
    const float* __restrict__ qkv, float* __restrict__ attw)
{
    const int kt = blockIdx.x, qt = blockIdx.y, bh = blockIdx.z;
    if (kt > qt) return;  // fully masked tiles: softmax writes the zeros
    const int b = bh >> 4, h = bh & 15;

    __shared__ float Qs[64][64 + 1];
    __shared__ float Ks[64][64 + 1];
    for (int i = threadIdx.x; i < 64 * 64; i += 256) {
        int r = i >> 6, d = i & 63;
        Qs[r][d] = qkv[(size_t)(b * SEQ + qt * 64 + r) * QKV_N + h * 64 + d];
        Ks[r][d] = qkv[(size_t)(b * SEQ + kt * 64 + r) * QKV_N + EMBED + h * 64 + d];
    }
    __syncthreads();

    const int tx = threadIdx.x & 15;
    const int ty = threadIdx.x >> 4;
    float acc[4][4] = {};
    #pragma unroll 8
    for (int d = 0; d < 64; ++d) {
        float a[4], bb[4];
        #pragma unroll
        for (int i = 0; i < 4; ++i) a[i] = Qs[ty * 4 + i][d];
        #pragma unroll
        for (int j = 0; j < 4; ++j) bb[j] = Ks[tx * 4 + j][d];
        #pragma unroll
        for (int i = 0; i < 4; ++i)
            #pragma unroll
            for (int j = 0; j < 4; ++j)
                acc[i][j] += a[i] * bb[j];
    }
    const size_t base = (size_t)bh * SEQ * SEQ;
    #pragma unroll
    for (int i = 0; i < 4; ++i) {
        int q = qt * 64 + ty * 4 + i;
        #pragma unroll
        for (int j = 0; j < 4; ++j) {
            int k = kt * 64 + tx * 4 + j;
            float s = acc[i][j] * 0.125f;
            if (k > q) s = -INFINITY;
            attw[base + (size_t)q * SEQ + k] = s;
        }
    }
}

// ---------------------------------------------------------------------------
// Row softmax in place. One block per (bh, q). Reads k in [0,q], writes full
// row of 2048 (exact 0.0f for k>q). Row values held in registers (<=8/thread).
// ---------------------------------------------------------------------------
__global__ __launch_bounds__(256) void softmax_kernel(float* __restrict__ attw)
{
    const int q = blockIdx.x;
    const int bh = blockIdx.y;
    const size_t rowp = ((size_t)bh * SEQ + q) * SEQ;
    const int n = q + 1;

    float v[8];
    int cnt = 0;
    float lmax = -INFINITY;
    for (int k = threadIdx.x; k < n; k += 256) {
        v[cnt] = attw[rowp + k];
        lmax = fmaxf(lmax, v[cnt]);
        ++cnt;
    }
    // wave reduce max
    #pragma unroll
    for (int off = 32; off > 0; off >>= 1)
        lmax = fmaxf(lmax, __shfl_down(lmax, off, 64));
    __shared__ float sred[4];
    const int lane = threadIdx.x & 63, wid = threadIdx.x >> 6;
    if (lane == 0) sred[wid] = lmax;
    __syncthreads();
    const float gmax = fmaxf(fmaxf(sred[0], sred[1]), fmaxf(sred[2], sred[3]));
    __syncthreads();

    float lsum = 0.0f;
    for (int i = 0; i < cnt; ++i) {
        v[i] = __expf(v[i] - gmax);   // exp(-inf - gmax) = 0 for masked-in-tile
        lsum += v[i];
    }
    #pragma unroll
    for (int off = 32; off > 0; off >>= 1)
        lsum += __shfl_down(lsum, off, 64);
    if (lane == 0) sred[wid] = lsum;
    __syncthreads();
    const float inv = 1.0f / (sred[0] + sred[1] + sred[2] + sred[3]);

    int idx = 0;
    for (int k = threadIdx.x; k < SEQ; k += 256) {
        float out = 0.0f;
        if (k < n) { out = v[idx] * inv; ++idx; }
        attw[rowp + k] = out;
    }
}

// ---------------------------------------------------------------------------
// attended = P @ V per (bh). Block per (qt, bh), 64x64 output (D=64),
// k-tiles only where kt<=qt (P==0 above diagonal).
// Writes attended in (tok, E) layout: att_out[m, h*64+d].
// ---------------------------------------------------------------------------
__global__ __launch_bounds__(256) void pv_kernel(
    const float* __restrict__ attw, const float* __restrict__ qkv,
    float* __restrict__ att_out)
{
    const int qt = blockIdx.x, bh = blockIdx.y;
    const int b = bh >> 4, h = bh & 15;
    __shared__ float Ps[64][64 + 1];
    __shared__ float Vs[64][64 + 1];
    const int tx = threadIdx.x & 15;
    const int ty = threadIdx.x >> 4;
    const size_t pbase = (size_t)bh * SEQ * SEQ;

    float acc[4][4] = {};
    for (int kt = 0; kt <= qt; ++kt) {
        for (int i = threadIdx.x; i < 64 * 64; i += 256) {
            int r = i >> 6, c = i & 63;
            Ps[r][c] = attw[pbase + (size_t)(qt * 64 + r) * SEQ + kt * 64 + c];
            Vs[r][c] = qkv[(size_t)(b * SEQ + kt * 64 + r) * QKV_N + 2 * EMBED + h * 64 + c];
        }
        __syncthreads();
        #pragma unroll 8
        for (int kk = 0; kk < 64; ++kk) {
            float a[4], bb[4];
            #pragma unroll
            for (int i = 0; i < 4; ++i) a[i] = Ps[ty * 4 + i][kk];
            #pragma unroll
            for (int j = 0; j < 4; ++j) bb[j] = Vs[kk][tx * 4 + j];
            #pragma unroll
            for (int i = 0; i < 4; ++i)
                #pragma unroll
                for (int j = 0; j < 4; ++j)
                    acc[i][j] += a[i] * bb[j];
        }
        __syncthreads();
    }
    #pragma unroll
    for (int i = 0; i < 4; ++i) {
        int m = b * SEQ + qt * 64 + ty * 4 + i;
        #pragma unroll
        for (int j = 0; j < 4; ++j)
            att_out[(size_t)m * EMBED + h * 64 + tx * 4 + j] = acc[i][j];
    }
}

extern "C" void kernel_launch(void* const* d_in, const int* in_sizes, int n_in,
                              void* d_out, int out_size, void* d_ws, size_t ws_size,
                              hipStream_t stream)
{
    const float* x     = (const float*)d_in[0];   // (2,2048,1024)
    const float* W_qkv = (const float*)d_in[1];   // (1024,3072)
    const float* b_qkv = (const float*)d_in[2];   // (3072,)
    const float* W_out = (const float*)d_in[3];   // (1024,1024)
    const float* b_out = (const float*)d_in[4];   // (1024,)

    float* out  = (float*)d_out;                  // (2,2048,1024)
    float* attw = out + OUT_ELEMS;                // (2,16,2048,2048)

    float* qkv     = (float*)d_ws;                        // 4096*3072 fp32 = 50.3 MB
    float* att_out = qkv + (size_t)M_TOK * QKV_N;         // 4096*1024 fp32 = 16.8 MB

    // 1. qkv = x @ W_qkv + b_qkv
    gemm_bias_kernel<<<dim3(QKV_N / 64, M_TOK / 64), 256, 0, stream>>>(
        x, W_qkv, b_qkv, qkv, M_TOK, QKV_N, EMBED);

    // 2. masked scores into attention-weights output region
    scores_kernel<<<dim3(SEQ / 64, SEQ / 64, BATCH * NHEAD), 256, 0, stream>>>(qkv, attw);

    // 3. causal softmax in place (writes exact zeros above diagonal)
    softmax_kernel<<<dim3(SEQ, BATCH * NHEAD), 256, 0, stream>>>(attw);

    // 4. attended = P @ V  -> (tok, E) layout
    pv_kernel<<<dim3(SEQ / 64, BATCH * NHEAD), 256, 0, stream>>>(attw, qkv, att_out);

    // 5. out = attended @ W_out + b_out
    gemm_bias_kernel<<<dim3(EMBED / 64, M_TOK / 64), 256, 0, stream>>>(
        att_out, W_out, b_out, out, M_TOK, EMBED, EMBED);
}

// Round 2
// 804.398 us; speedup vs baseline: 2.7672x; 2.7672x over previous
//
#include <hip/hip_runtime.h>
#include <hip/hip_bf16.h>
#include <math.h>

#define BATCH 2
#define SEQ 2048
#define EMBED 1024
#define NHEAD 16
#define QKV_N 3072
#define M_TOK 4096
#define OUT_ELEMS ((size_t)M_TOK * EMBED)

typedef __attribute__((ext_vector_type(4))) float f32x4;
typedef __attribute__((ext_vector_type(8))) short bf16x8;

__device__ __forceinline__ short f2bf(float f) {
    __hip_bfloat16 h = __float2bfloat16(f);
    return *reinterpret_cast<short*>(&h);
}

// async global->LDS, 16B per lane; LDS dest = wave-uniform base + lane*16
__device__ __forceinline__ void gld16(const void* g, void* l) {
    __builtin_amdgcn_global_load_lds(
        (const __attribute__((address_space(1))) unsigned int*)g,
        (__attribute__((address_space(3))) unsigned int*)l, 16, 0, 0);
}

// ---------------------------------------------------------------------------
// fp32 -> bf16 cast, 4 elems/thread
// ---------------------------------------------------------------------------
__global__ __launch_bounds__(256) void cast_bf16_kernel(
    const float* __restrict__ in, short* __restrict__ out, int n4)
{
    int i = blockIdx.x * 256 + threadIdx.x;
    if (i >= n4) return;
    float4 v = ((const float4*)in)[i];
    unsigned long long pk =
        (unsigned long long)(unsigned short)f2bf(v.x)
      | ((unsigned long long)(unsigned short)f2bf(v.y) << 16)
      | ((unsigned long long)(unsigned short)f2bf(v.z) << 32)
      | ((unsigned long long)(unsigned short)f2bf(v.w) << 48);
    ((unsigned long long*)out)[i] = pk;
}

// ---------------------------------------------------------------------------
// Transpose+cast: in[R][C] fp32 -> out[C][R] bf16. 64x64 tiles.
// ---------------------------------------------------------------------------
__global__ __launch_bounds__(256) void transpose_cast_kernel(
    const float* __restrict__ in, short* __restrict__ out, int R, int C)
{
    __shared__ float t[64][65];
    const int r0 = blockIdx.y * 64, c0 = blockIdx.x * 64;
    for (int i = threadIdx.x; i < 4096; i += 256) {
        int r = i >> 6, c = i & 63;
        t[r][c] = in[(size_t)(r0 + r) * C + c0 + c];
    }
    __syncthreads();
    for (int i = threadIdx.x; i < 4096; i += 256) {
        int c = i >> 6, r = i & 63;
        out[(size_t)(c0 + c) * R + r0 + r] = f2bf(t[r][c]);
    }
}

// ---------------------------------------------------------------------------
// bf16 MFMA GEMM (m97 structure): C[M][N] = A[M][K] @ Bt[N][K]^T + bias
// 128x128 tile, BK=32, 256 thr (4 waves 2x2), 16x16x32 MFMA, global_load_lds.
// ---------------------------------------------------------------------------
template <bool OUT_BF16>
__global__ __launch_bounds__(256) void gemm_mfma_kernel(
    const short* __restrict__ A, const short* __restrict__ Bt,
    const float* __restrict__ bias, void* __restrict__ C,
    int M, int N, int K)
{
    __shared__ short As[128 * 32];
    __shared__ short Bs[128 * 32];
    const int tid = threadIdx.x;
    const int w = tid >> 6, lane = tid & 63;
    const int quad = lane >> 4, lc = lane & 15;
    const int wm = w & 1, wn = w >> 1;
    const int m0 = blockIdx.y * 128, n0 = blockIdx.x * 128;

    f32x4 acc[4][4] = {};

    const int srow = (lane >> 2);       // 0..15 within a 16-row staging inst
    const int skp = (lane & 3) * 8;     // k-part, 8 elems = 16B

    for (int k0 = 0; k0 < K; k0 += 32) {
        #pragma unroll
        for (int j = 0; j < 2; ++j) {
            int r = w * 32 + j * 16 + srow;
            gld16(A + ((size_t)(m0 + r) * K + k0 + skp), &As[(w * 32 + j * 16) * 32]);
            gld16(Bt + ((size_t)(n0 + r) * K + k0 + skp), &Bs[(w * 32 + j * 16) * 32]);
        }
        __syncthreads();
        bf16x8 af[4], bf[4];
        #pragma unroll
        for (int i = 0; i < 4; ++i)
            af[i] = *(const bf16x8*)&As[(wm * 64 + i * 16 + lc) * 32 + quad * 8];
        #pragma unroll
        for (int i = 0; i < 4; ++i)
            bf[i] = *(const bf16x8*)&Bs[(wn * 64 + i * 16 + lc) * 32 + quad * 8];
        #pragma unroll
        for (int mi = 0; mi < 4; ++mi)
            #pragma unroll
            for (int ni = 0; ni < 4; ++ni)
                acc[mi][ni] = __builtin_amdgcn_mfma_f32_16x16x32_bf16(
                    af[mi], bf[ni], acc[mi][ni], 0, 0, 0);
        __syncthreads();
    }

    #pragma unroll
    for (int mi = 0; mi < 4; ++mi) {
        int row = m0 + wm * 64 + mi * 16 + quad * 4;
        #pragma unroll
        for (int ni = 0; ni < 4; ++ni) {
            int col = n0 + wn * 64 + ni * 16 + lc;
            float bc = bias[col];
            #pragma unroll
            for (int r = 0; r < 4; ++r) {
                float v = acc[mi][ni][r] + bc;
                if (OUT_BF16)
                    ((short*)C)[(size_t)(row + r) * N + col] = f2bf(v);
                else
                    ((float*)C)[(size_t)(row + r) * N + col] = v;
            }
        }
    }
}

// ---------------------------------------------------------------------------
// Fused causal attention, two-pass flash. Block = (qt, bh), 64 q-rows,
// 4 waves x 16 q-rows. Writes P (fp32) once + attended (bf16).
// ---------------------------------------------------------------------------
__global__ __launch_bounds__(256) void attn_kernel(
    const short* __restrict__ qkvb,   // [4096][3072] bf16
    float* __restrict__ attw,         // [32][2048][2048]
    short* __restrict__ attb)         // [4096][1024] bf16
{
    const int qt = gridDim.x - 1 - blockIdx.x;   // heavy tiles first
    const int bh = blockIdx.y;
    const int b = bh >> 4, h = bh & 15;
    const int tid = threadIdx.x;
    const int w = tid >> 6, lane = tid & 63;
    const int quad = lane >> 4, lc = lane & 15;
    const int qloc = w * 16 + quad * 4;          // + r = q within 64-tile

    __shared__ short Kb[64 * 64];      // [key][d]
    __shared__ short Vt[64 * 72];      // [d][key], pad 8
    __shared__ short Ps[4][16 * 72];   // per-wave P [q][key], pad 8

    // Q fragments, held in registers for both passes
    const short* qptr = qkvb + (size_t)(b * SEQ + qt * 64 + w * 16 + lc) * QKV_N
                        + h * 64 + quad * 8;
    const bf16x8 qf0 = *(const bf16x8*)qptr;
    const bf16x8 qf1 = *(const bf16x8*)(qptr + 32);

    float m_i[4], l_i[4];
    #pragma unroll
    for (int r = 0; r < 4; ++r) { m_i[r] = -INFINITY; l_i[r] = 0.f; }

    // ---------------- pass 1: row max & sum ----------------
    for (int kt = 0; kt <= qt; ++kt) {
        __syncthreads();
        #pragma unroll
        for (int j = 0; j < 2; ++j) {
            int row = w * 16 + j * 8 + (lane >> 3);
            const short* g = qkvb + (size_t)(b * SEQ + kt * 64 + row) * QKV_N
                             + EMBED + h * 64 + (lane & 7) * 8;
            gld16(g, &Kb[(w * 16 + j * 8) * 64]);
        }
        __syncthreads();

        const bool diag = (kt == qt);
        float sv[4][4];
        #pragma unroll
        for (int ni = 0; ni < 4; ++ni) {
            f32x4 acc = 0;
            bf16x8 kf0 = *(const bf16x8*)&Kb[(ni * 16 + lc) * 64 + quad * 8];
            bf16x8 kf1 = *(const bf16x8*)&Kb[(ni * 16 + lc) * 64 + 32 + quad * 8];
            acc = __builtin_amdgcn_mfma_f32_16x16x32_bf16(qf0, kf0, acc, 0, 0, 0);
            acc = __builtin_amdgcn_mfma_f32_16x16x32_bf16(qf1, kf1, acc, 0, 0, 0);
            #pragma unroll
            for (int r = 0; r < 4; ++r) {
                float v = acc[r] * 0.125f;
                if (diag && (ni * 16 + lc) > (qloc + r)) v = -INFINITY;
                sv[ni][r] = v;
            }
        }
        #pragma unroll
        for (int r = 0; r < 4; ++r) {
            float mx = fmaxf(fmaxf(sv[0][r], sv[1][r]), fmaxf(sv[2][r], sv[3][r]));
            #pragma unroll
            for (int d = 1; d <= 8; d <<= 1) mx = fmaxf(mx, __shfl_xor(mx, d, 64));
            float mn = fmaxf(m_i[r], mx);
            float s = __expf(sv[0][r] - mn) + __expf(sv[1][r] - mn)
                    + __expf(sv[2][r] - mn) + __expf(sv[3][r] - mn);
            #pragma unroll
            for (int d = 1; d <= 8; d <<= 1) s += __shfl_xor(s, d, 64);
            l_i[r] = l_i[r] * __expf(m_i[r] - mn) + s;
            m_i[r] = mn;
        }
    }

    float inv_l[4];
    #pragma unroll
    for (int r = 0; r < 4; ++r) inv_l[r] = 1.0f / l_i[r];

    // ---------------- pass 2: P write + P@V ----------------
    f32x4 o[4] = {};
    for (int kt = 0; kt <= qt; ++kt) {
        __syncthreads();
        #pragma unroll
        for (int j = 0; j < 2; ++j) {
            int row = w * 16 + j * 8 + (lane >> 3);
            const short* g = qkvb + (size_t)(b * SEQ + kt * 64 + row) * QKV_N
                             + EMBED + h * 64 + (lane & 7) * 8;
            gld16(g, &Kb[(w * 16 + j * 8) * 64]);
        }
        {   // V tile, transposed into LDS [d][key]
            int key = tid & 63, dg = tid >> 6;
            const short* vs = qkvb + (size_t)(b * SEQ + kt * 64 + key) * QKV_N
                              + 2 * EMBED + h * 64 + dg * 16;
            bf16x8 v0 = *(const bf16x8*)vs;
            bf16x8 v1 = *(const bf16x8*)(vs + 8);
            #pragma unroll
            for (int jj = 0; jj < 8; ++jj) {
                Vt[(dg * 16 + jj) * 72 + key] = v0[jj];
                Vt[(dg * 16 + 8 + jj) * 72 + key] = v1[jj];
            }
        }
        __syncthreads();

        const bool diag = (kt == qt);
        short* Psw = Ps[w];
        #pragma unroll
        for (int ni = 0; ni < 4; ++ni) {
            f32x4 acc = 0;
            bf16x8 kf0 = *(const bf16x8*)&Kb[(ni * 16 + lc) * 64 + quad * 8];
            bf16x8 kf1 = *(const bf16x8*)&Kb[(ni * 16 + lc) * 64 + 32 + quad * 8];
            acc = __builtin_amdgcn_mfma_f32_16x16x32_bf16(qf0, kf0, acc, 0, 0, 0);
            acc = __builtin_amdgcn_mfma_f32_16x16x32_bf16(qf1, kf1, acc, 0, 0, 0);
            #pragma unroll
            for (int r = 0; r < 4; ++r) {
                float v = acc[r] * 0.125f;
                bool msk = diag && (ni * 16 + lc) > (qloc + r);
                float p = msk ? 0.f : __expf(v - m_i[r]) * inv_l[r];
                attw[((size_t)bh * SEQ + qt * 64 + qloc + r) * SEQ
                     + kt * 64 + ni * 16 + lc] = p;
                Psw[(quad * 4 + r) * 72 + ni * 16 + lc] = f2bf(p);
            }
        }
        // P (A-layout via LDS) @ V
        #pragma unroll
        for (int kd = 0; kd < 2; ++kd) {
            bf16x8 pf = *(const bf16x8*)&Psw[lc * 72 + kd * 32 + quad * 8];
            #pragma unroll
            for (int ni = 0; ni < 4; ++ni) {
                bf16x8 vf = *(const bf16x8*)&Vt[(ni * 16 + lc) * 72 + kd * 32 + quad * 8];
                o[ni] = __builtin_amdgcn_mfma_f32_16x16x32_bf16(pf, vf, o[ni], 0, 0, 0);
            }
        }
    }

    // attended -> bf16 [tok][E]
    #pragma unroll
    for (int ni = 0; ni < 4; ++ni)
        #pragma unroll
        for (int r = 0; r < 4; ++r)
            attb[(size_t)(b * SEQ + qt * 64 + qloc + r) * EMBED
                 + h * 64 + ni * 16 + lc] = f2bf(o[ni][r]);

    // zero-fill strictly-upper k-tiles (k >= (qt+1)*64)
    if (qt < (int)gridDim.x - 1) {
        const int zc4 = (qt + 1) * 16;
        for (int r = 0; r < 64; ++r) {
            f32x4* rowp = (f32x4*)(attw + ((size_t)bh * SEQ + qt * 64 + r) * SEQ);
            for (int c = zc4 + tid; c < 512; c += 256) rowp[c] = 0;
        }
    }
}

extern "C" void kernel_launch(void* const* d_in, const int* in_sizes, int n_in,
                              void* d_out, int out_size, void* d_ws, size_t ws_size,
                              hipStream_t stream)
{
    const float* x     = (const float*)d_in[0];
    const float* W_qkv = (const float*)d_in[1];
    const float* b_qkv = (const float*)d_in[2];
    const float* W_out = (const float*)d_in[3];
    const float* b_out = (const float*)d_in[4];

    float* out  = (float*)d_out;
    float* attw = out + OUT_ELEMS;

    short* xb   = (short*)d_ws;                       // 4096x1024
    short* wqt  = xb + (size_t)M_TOK * EMBED;         // 3072x1024 (W_qkv^T)
    short* wot  = wqt + (size_t)QKV_N * EMBED;        // 1024x1024 (W_out^T)
    short* qkvb = wot + (size_t)EMBED * EMBED;        // 4096x3072
    short* attb = qkvb + (size_t)M_TOK * QKV_N;       // 4096x1024

    cast_bf16_kernel<<<OUT_ELEMS / 4 / 256, 256, 0, stream>>>(x, xb, (int)(OUT_ELEMS / 4));
    transpose_cast_kernel<<<dim3(QKV_N / 64, EMBED / 64), 256, 0, stream>>>(W_qkv, wqt, EMBED, QKV_N);
    transpose_cast_kernel<<<dim3(EMBED / 64, EMBED / 64), 256, 0, stream>>>(W_out, wot, EMBED, EMBED);

    gemm_mfma_kernel<true><<<dim3(QKV_N / 128, M_TOK / 128), 256, 0, stream>>>(
        xb, wqt, b_qkv, qkvb, M_TOK, QKV_N, EMBED);

    attn_kernel<<<dim3(SEQ / 64, BATCH * NHEAD), 256, 0, stream>>>(qkvb, attw, attb);

    gemm_mfma_kernel<false><<<dim3(EMBED / 128, M_TOK / 128), 256, 0, stream>>>(
        attb, wot, b_out, out, M_TOK, EMBED, EMBED);
}